// Round 4
// baseline (1710.833 us; speedup 1.0000x reference)
//
#include <hip/hip_runtime.h>
#include <math.h>

#define DCH 64

// ---------------- CSR build ----------------
// edge_index arrives as int32 (harness converts int64 -> int32):
//   ei[e] = src, ei[E + e] = dst.

__global__ void zero_kernel(int* __restrict__ p, int n) {
    int i = blockIdx.x * blockDim.x + threadIdx.x;
    if (i < n) p[i] = 0;
}

__global__ void hist_kernel(const int* __restrict__ ei, int* __restrict__ cnt, int E) {
    int stride = gridDim.x * blockDim.x;
    for (int e = blockIdx.x * blockDim.x + threadIdx.x; e < E; e += stride) {
        int d = ei[(size_t)E + e];
        atomicAdd(&cnt[d], 1);
    }
}

__global__ void scan1_kernel(const int* __restrict__ cnt, int* __restrict__ offs,
                             int* __restrict__ partial, int n) {
    __shared__ int sh[1024];
    int i = blockIdx.x * 1024 + threadIdx.x;
    int val = (i < n) ? cnt[i] : 0;
    sh[threadIdx.x] = val;
    __syncthreads();
    for (int d = 1; d < 1024; d <<= 1) {
        int t = (threadIdx.x >= d) ? sh[threadIdx.x - d] : 0;
        __syncthreads();
        sh[threadIdx.x] += t;
        __syncthreads();
    }
    if (i < n) offs[i] = sh[threadIdx.x] - val;   // exclusive within block
    if (threadIdx.x == 1023) partial[blockIdx.x] = sh[1023];
}

__global__ void scan2_kernel(int* __restrict__ partial, int* __restrict__ total, int nb) {
    __shared__ int sh[1024];
    int val = (threadIdx.x < nb) ? partial[threadIdx.x] : 0;
    sh[threadIdx.x] = val;
    __syncthreads();
    for (int d = 1; d < 1024; d <<= 1) {
        int t = (threadIdx.x >= d) ? sh[threadIdx.x - d] : 0;
        __syncthreads();
        sh[threadIdx.x] += t;
        __syncthreads();
    }
    if (threadIdx.x < nb) partial[threadIdx.x] = sh[threadIdx.x] - val; // exclusive block offsets
    if (threadIdx.x == 1023) *total = sh[1023];
}

__global__ void scan3_kernel(int* __restrict__ offs, const int* __restrict__ partial, int n) {
    int i = blockIdx.x * 1024 + threadIdx.x;
    if (i < n) offs[i] += partial[blockIdx.x];
}

__global__ void scatter_kernel(const int* __restrict__ ei, const int* __restrict__ offs,
                               int* __restrict__ fill, int* __restrict__ ssrc, int E) {
    int stride = gridDim.x * blockDim.x;
    for (int e = blockIdx.x * blockDim.x + threadIdx.x; e < E; e += stride) {
        int s = ei[e];
        int d = ei[(size_t)E + e];
        int pos = offs[d] + atomicAdd(&fill[d], 1);
        ssrc[pos] = s;
    }
}

// ---------------- fused q/k/v/skip linear ----------------
// block = 256 (4 waves). Wave w computes output matrix w for a 64-node chunk.
// Lane = output channel; that lane's W row lives in 64 VGPRs; x rows staged in
// LDS and broadcast-read as float4. The skip projection (wave 3) is written
// straight into the attention-output buffer; attn later updates it in place.

__global__ void linear4_kernel(const float* __restrict__ x,
                               const float* __restrict__ Wq, const float* __restrict__ bq,
                               const float* __restrict__ Wk, const float* __restrict__ bk,
                               const float* __restrict__ Wv, const float* __restrict__ bv,
                               const float* __restrict__ Ws, const float* __restrict__ bs,
                               float* __restrict__ oq, float* __restrict__ ok,
                               float* __restrict__ ov, float* __restrict__ os,
                               int n) {
    __shared__ float xs[64 * DCH];
    const int tid = threadIdx.x;
    const int wave = tid >> 6;
    const int lane = tid & 63;
    const float* W; const float* b; float* out;
    if (wave == 0)      { W = Wq; b = bq; out = oq; }
    else if (wave == 1) { W = Wk; b = bk; out = ok; }
    else if (wave == 2) { W = Wv; b = bv; out = ov; }
    else                { W = Ws; b = bs; out = os; }
    float bias = b[lane];
    float wr[64];
    #pragma unroll
    for (int i4 = 0; i4 < 16; ++i4) {
        float4 t = *(const float4*)&W[lane * DCH + i4 * 4];
        wr[i4*4+0] = t.x; wr[i4*4+1] = t.y; wr[i4*4+2] = t.z; wr[i4*4+3] = t.w;
    }
    int base = blockIdx.x * 64;
    int nn = n - base; if (nn > 64) nn = 64;
    const float4* xg = (const float4*)(x + (size_t)base * DCH);
    float4* xs4 = (float4*)xs;
    for (int i = tid; i < nn * (DCH/4); i += 256) xs4[i] = xg[i];
    __syncthreads();
    for (int j = 0; j < nn; ++j) {
        float acc = bias;
        #pragma unroll
        for (int i4 = 0; i4 < 16; ++i4) {
            float4 xv = *(const float4*)&xs[j * DCH + i4 * 4];
            acc += xv.x * wr[i4*4+0] + xv.y * wr[i4*4+1]
                 + xv.z * wr[i4*4+2] + xv.w * wr[i4*4+3];
        }
        out[(size_t)(base + j) * DCH + lane] = acc;
    }
}

// ---------------- per-node online-softmax attention ----------------
// One wave per dst node. 4 groups of 16 lanes; each group walks every 4th
// incoming edge with its own online-softmax state (m, den, num[4] f32 per lane
// = 64 channels per group). Cross-group merge via shfl_xor(16,32).
// `io` holds the skip projection on entry and the layer output on exit.

__global__ void attn_kernel(const float* __restrict__ q, const float* __restrict__ k,
                            const float* __restrict__ v,
                            const int* __restrict__ offs, const int* __restrict__ ssrc,
                            float* __restrict__ io, int n, int do_relu) {
    const int tid = threadIdx.x;
    const int lane = tid & 63;
    const int g = lane >> 4;
    const int gl = lane & 15;
    int node = blockIdx.x * (blockDim.x >> 6) + (tid >> 6);
    if (node >= n) return;
    int e0 = offs[node], e1 = offs[node + 1];
    float4 qv = *(const float4*)&q[(size_t)node * DCH + gl * 4];
    float m = -INFINITY, den = 0.f;
    float nx = 0.f, ny = 0.f, nz = 0.f, nw = 0.f;
    for (int e = e0 + g; e < e1; e += 4) {
        int src = ssrc[e];
        float4 kv = *(const float4*)&k[(size_t)src * DCH + gl * 4];
        float dot = qv.x*kv.x + qv.y*kv.y + qv.z*kv.z + qv.w*kv.w;
        dot += __shfl_xor(dot, 1);
        dot += __shfl_xor(dot, 2);
        dot += __shfl_xor(dot, 4);
        dot += __shfl_xor(dot, 8);
        float s = dot * 0.125f;           // 1/sqrt(64)
        float mn = fmaxf(m, s);
        float c = __expf(m - mn);         // first iter: exp(-inf) = 0
        float p = __expf(s - mn);
        float4 vv = *(const float4*)&v[(size_t)src * DCH + gl * 4];
        nx = nx * c + p * vv.x;
        ny = ny * c + p * vv.y;
        nz = nz * c + p * vv.z;
        nw = nw * c + p * vv.w;
        den = den * c + p;
        m = mn;
    }
    // merge the 4 group-partials (guard empty groups: den==0 -> weight 0)
    #pragma unroll
    for (int delta = 16; delta <= 32; delta <<= 1) {
        float mo   = __shfl_xor(m, delta);
        float deno = __shfl_xor(den, delta);
        float nxo  = __shfl_xor(nx, delta);
        float nyo  = __shfl_xor(ny, delta);
        float nzo  = __shfl_xor(nz, delta);
        float nwo  = __shfl_xor(nw, delta);
        float mn = fmaxf(m, mo);
        float c  = (den  > 0.f) ? __expf(m  - mn) : 0.f;
        float co = (deno > 0.f) ? __expf(mo - mn) : 0.f;
        nx = nx * c + nxo * co;
        ny = ny * c + nyo * co;
        nz = nz * c + nzo * co;
        nw = nw * c + nwo * co;
        den = den * c + deno * co;
        m = mn;
    }
    float4 skv = *(const float4*)&io[(size_t)node * DCH + gl * 4];
    float inv = (den > 0.f) ? 1.f / den : 0.f;   // empty node -> skip only
    float4 o;
    o.x = nx * inv + skv.x;
    o.y = ny * inv + skv.y;
    o.z = nz * inv + skv.z;
    o.w = nw * inv + skv.w;
    if (do_relu) {
        o.x = fmaxf(o.x, 0.f); o.y = fmaxf(o.y, 0.f);
        o.z = fmaxf(o.z, 0.f); o.w = fmaxf(o.w, 0.f);
    }
    if (lane < 16) *(float4*)&io[(size_t)node * DCH + gl * 4] = o;
}

// ---------------- launch ----------------

extern "C" void kernel_launch(void* const* d_in, const int* in_sizes, int n_in,
                              void* d_out, int out_size, void* d_ws, size_t ws_size,
                              hipStream_t stream) {
    const float* x   = (const float*)d_in[0];
    const int*   ei  = (const int*)d_in[1];      // int32 per harness contract
    const float* Wq1 = (const float*)d_in[2];  const float* bq1 = (const float*)d_in[3];
    const float* Wk1 = (const float*)d_in[4];  const float* bk1 = (const float*)d_in[5];
    const float* Wv1 = (const float*)d_in[6];  const float* bv1 = (const float*)d_in[7];
    const float* Ws1 = (const float*)d_in[8];  const float* bs1 = (const float*)d_in[9];
    const float* Wq2 = (const float*)d_in[10]; const float* bq2 = (const float*)d_in[11];
    const float* Wk2 = (const float*)d_in[12]; const float* bk2 = (const float*)d_in[13];
    const float* Wv2 = (const float*)d_in[14]; const float* bv2 = (const float*)d_in[15];
    const float* Ws2 = (const float*)d_in[16]; const float* bs2 = (const float*)d_in[17];
    int N = in_sizes[0] / DCH;
    int E = in_sizes[1] / 2;

    char* p = (char*)d_ws;
    auto alloc = [&](size_t bytes) -> void* {
        void* r = (void*)p; p += (bytes + 255) & ~(size_t)255; return r;
    };
    float* q    = (float*)alloc((size_t)N * DCH * 4);
    float* kbuf = (float*)alloc((size_t)N * DCH * 4);
    float* vbuf = (float*)alloc((size_t)N * DCH * 4);
    float* h    = (float*)alloc((size_t)N * DCH * 4);
    int* cnt  = (int*)alloc((size_t)N * 4);
    int* fill = (int*)alloc((size_t)N * 4);
    int* offs = (int*)alloc((size_t)(N + 1) * 4);
    int* part = (int*)alloc(1024 * 4);
    int* ssrc = (int*)alloc((size_t)E * 4);
    float* outp = (float*)d_out;

    int nb = (N + 1023) / 1024;

    // CSR by dst (rebuilt every call; ws is re-poisoned before each launch)
    hipLaunchKernelGGL(zero_kernel, dim3((N + 255) / 256), dim3(256), 0, stream, cnt, N);
    hipLaunchKernelGGL(zero_kernel, dim3((N + 255) / 256), dim3(256), 0, stream, fill, N);
    hipLaunchKernelGGL(hist_kernel, dim3(1024), dim3(256), 0, stream, ei, cnt, E);
    hipLaunchKernelGGL(scan1_kernel, dim3(nb), dim3(1024), 0, stream, cnt, offs, part, N);
    hipLaunchKernelGGL(scan2_kernel, dim3(1), dim3(1024), 0, stream, part, offs + N, nb);
    hipLaunchKernelGGL(scan3_kernel, dim3(nb), dim3(1024), 0, stream, offs, part, N);
    hipLaunchKernelGGL(scatter_kernel, dim3(1024), dim3(256), 0, stream, ei, offs, fill, ssrc, E);

    // layer 1 (skip -> h, attn updates h in place, ReLU)
    hipLaunchKernelGGL(linear4_kernel, dim3((N + 63) / 64), dim3(256), 0, stream,
                       x, Wq1, bq1, Wk1, bk1, Wv1, bv1, Ws1, bs1,
                       q, kbuf, vbuf, h, N);
    hipLaunchKernelGGL(attn_kernel, dim3((N + 3) / 4), dim3(256), 0, stream,
                       q, kbuf, vbuf, offs, ssrc, h, N, 1);

    // layer 2 (skip -> d_out, attn updates d_out in place)
    hipLaunchKernelGGL(linear4_kernel, dim3((N + 63) / 64), dim3(256), 0, stream,
                       h, Wq2, bq2, Wk2, bk2, Wv2, bv2, Ws2, bs2,
                       q, kbuf, vbuf, outp, N);
    hipLaunchKernelGGL(attn_kernel, dim3((N + 3) / 4), dim3(256), 0, stream,
                       q, kbuf, vbuf, offs, ssrc, outp, N, 0);
}

// Round 7
// 950.887 us; speedup vs baseline: 1.7992x; 1.7992x over previous
//
#include <hip/hip_runtime.h>
#include <math.h>

#define DCH 64

// ---------------- CSR build ----------------
// edge_index arrives as int32 (harness converts int64 -> int32):
//   ei[e] = src, ei[E + e] = dst.

__global__ void zero_kernel(int* __restrict__ p, int n) {
    int i = blockIdx.x * blockDim.x + threadIdx.x;
    if (i < n) p[i] = 0;
}

__global__ void hist_kernel(const int* __restrict__ ei, int* __restrict__ cnt, int E) {
    int stride = gridDim.x * blockDim.x;
    for (int e = blockIdx.x * blockDim.x + threadIdx.x; e < E; e += stride) {
        int d = ei[(size_t)E + e];
        atomicAdd(&cnt[d], 1);
    }
}

__global__ void scan1_kernel(const int* __restrict__ cnt, int* __restrict__ offs,
                             int* __restrict__ partial, int n) {
    __shared__ int sh[1024];
    int i = blockIdx.x * 1024 + threadIdx.x;
    int val = (i < n) ? cnt[i] : 0;
    sh[threadIdx.x] = val;
    __syncthreads();
    for (int d = 1; d < 1024; d <<= 1) {
        int t = (threadIdx.x >= d) ? sh[threadIdx.x - d] : 0;
        __syncthreads();
        sh[threadIdx.x] += t;
        __syncthreads();
    }
    if (i < n) offs[i] = sh[threadIdx.x] - val;   // exclusive within block
    if (threadIdx.x == 1023) partial[blockIdx.x] = sh[1023];
}

__global__ void scan2_kernel(int* __restrict__ partial, int* __restrict__ total, int nb) {
    __shared__ int sh[1024];
    int val = (threadIdx.x < nb) ? partial[threadIdx.x] : 0;
    sh[threadIdx.x] = val;
    __syncthreads();
    for (int d = 1; d < 1024; d <<= 1) {
        int t = (threadIdx.x >= d) ? sh[threadIdx.x - d] : 0;
        __syncthreads();
        sh[threadIdx.x] += t;
        __syncthreads();
    }
    if (threadIdx.x < nb) partial[threadIdx.x] = sh[threadIdx.x] - val; // exclusive block offsets
    if (threadIdx.x == 1023) *total = sh[1023];
}

__global__ void scan3_kernel(int* __restrict__ offs, const int* __restrict__ partial, int n) {
    int i = blockIdx.x * 1024 + threadIdx.x;
    if (i < n) offs[i] += partial[blockIdx.x];
}

__global__ void scatter_kernel(const int* __restrict__ ei, const int* __restrict__ offs,
                               int* __restrict__ fill, int* __restrict__ ssrc, int E) {
    int stride = gridDim.x * blockDim.x;
    for (int e = blockIdx.x * blockDim.x + threadIdx.x; e < E; e += stride) {
        int s = ei[e];
        int d = ei[(size_t)E + e];
        int pos = offs[d] + atomicAdd(&fill[d], 1);
        ssrc[pos] = s;
    }
}

// ---------------- fused q/k/v/skip linear (lane = node) ----------------
// One thread per node. x-row lives in 64 statically-indexed VGPRs (no spill:
// round-4 counters showed VGPR_Count=64 with a per-lane wr[64] array -> scratch
// spill -> 1.03 GB FETCH and 640 us). W addresses are thread-independent ->
// hipcc scalarizes to s_load; W value is the free SGPR operand of v_fmac.
// 4 output channels at a time = 4 independent FMA chains (hide 4-cyc latency).
// The skip projection (m=3) is written straight to the attention-output buffer.

__global__ __launch_bounds__(64, 4)
void linear4_kernel(const float* __restrict__ x,
                    const float* __restrict__ Wq, const float* __restrict__ bq,
                    const float* __restrict__ Wk, const float* __restrict__ bk,
                    const float* __restrict__ Wv, const float* __restrict__ bv,
                    const float* __restrict__ Ws, const float* __restrict__ bs,
                    float* __restrict__ oq, float* __restrict__ ok,
                    float* __restrict__ ov, float* __restrict__ os,
                    int n) {
    int node = blockIdx.x * 64 + threadIdx.x;
    if (node >= n) return;
    float xr[64];
    const float4* xg = (const float4*)(x + (size_t)node * DCH);
    #pragma unroll
    for (int i = 0; i < 16; ++i) {
        float4 t = xg[i];
        xr[i*4+0] = t.x; xr[i*4+1] = t.y; xr[i*4+2] = t.z; xr[i*4+3] = t.w;
    }
    #pragma unroll
    for (int m = 0; m < 4; ++m) {
        const float* W; const float* b; float* o;
        if (m == 0)      { W = Wq; b = bq; o = oq; }
        else if (m == 1) { W = Wk; b = bk; o = ok; }
        else if (m == 2) { W = Wv; b = bv; o = ov; }
        else             { W = Ws; b = bs; o = os; }
        float4* out = (float4*)(o + (size_t)node * DCH);
        for (int c4 = 0; c4 < 16; ++c4) {
            const float* w0 = W + (c4 * 4 + 0) * DCH;
            const float* w1 = W + (c4 * 4 + 1) * DCH;
            const float* w2 = W + (c4 * 4 + 2) * DCH;
            const float* w3 = W + (c4 * 4 + 3) * DCH;
            float a0 = b[c4*4+0], a1 = b[c4*4+1], a2 = b[c4*4+2], a3 = b[c4*4+3];
            #pragma unroll
            for (int kk = 0; kk < 64; ++kk) {
                float xv = xr[kk];
                a0 += xv * w0[kk];
                a1 += xv * w1[kk];
                a2 += xv * w2[kk];
                a3 += xv * w3[kk];
            }
            float4 r; r.x = a0; r.y = a1; r.z = a2; r.w = a3;
            out[c4] = r;
        }
    }
}

// ---------------- per-node online-softmax attention ----------------
// One wave per dst node. 4 groups of 16 lanes; each group walks every 4th
// incoming edge with its own online-softmax state (m, den, num[4] f32 per lane
// = 64 channels per group). Cross-group merge via shfl_xor(16,32).
// `io` holds the skip projection on entry and the layer output on exit.

__global__ void attn_kernel(const float* __restrict__ q, const float* __restrict__ k,
                            const float* __restrict__ v,
                            const int* __restrict__ offs, const int* __restrict__ ssrc,
                            float* __restrict__ io, int n, int do_relu) {
    const int tid = threadIdx.x;
    const int lane = tid & 63;
    const int g = lane >> 4;
    const int gl = lane & 15;
    int node = blockIdx.x * (blockDim.x >> 6) + (tid >> 6);
    if (node >= n) return;
    int e0 = offs[node], e1 = offs[node + 1];
    float4 qv = *(const float4*)&q[(size_t)node * DCH + gl * 4];
    float m = -INFINITY, den = 0.f;
    float nx = 0.f, ny = 0.f, nz = 0.f, nw = 0.f;
    for (int e = e0 + g; e < e1; e += 4) {
        int src = ssrc[e];
        float4 kv = *(const float4*)&k[(size_t)src * DCH + gl * 4];
        float dot = qv.x*kv.x + qv.y*kv.y + qv.z*kv.z + qv.w*kv.w;
        dot += __shfl_xor(dot, 1);
        dot += __shfl_xor(dot, 2);
        dot += __shfl_xor(dot, 4);
        dot += __shfl_xor(dot, 8);
        float s = dot * 0.125f;           // 1/sqrt(64)
        float mn = fmaxf(m, s);
        float c = __expf(m - mn);         // first iter: exp(-inf) = 0
        float p = __expf(s - mn);
        float4 vv = *(const float4*)&v[(size_t)src * DCH + gl * 4];
        nx = nx * c + p * vv.x;
        ny = ny * c + p * vv.y;
        nz = nz * c + p * vv.z;
        nw = nw * c + p * vv.w;
        den = den * c + p;
        m = mn;
    }
    // merge the 4 group-partials (guard empty groups: den==0 -> weight 0)
    #pragma unroll
    for (int delta = 16; delta <= 32; delta <<= 1) {
        float mo   = __shfl_xor(m, delta);
        float deno = __shfl_xor(den, delta);
        float nxo  = __shfl_xor(nx, delta);
        float nyo  = __shfl_xor(ny, delta);
        float nzo  = __shfl_xor(nz, delta);
        float nwo  = __shfl_xor(nw, delta);
        float mn = fmaxf(m, mo);
        float c  = (den  > 0.f) ? __expf(m  - mn) : 0.f;
        float co = (deno > 0.f) ? __expf(mo - mn) : 0.f;
        nx = nx * c + nxo * co;
        ny = ny * c + nyo * co;
        nz = nz * c + nzo * co;
        nw = nw * c + nwo * co;
        den = den * c + deno * co;
        m = mn;
    }
    float4 skv = *(const float4*)&io[(size_t)node * DCH + gl * 4];
    float inv = (den > 0.f) ? 1.f / den : 0.f;   // empty node -> skip only
    float4 o;
    o.x = nx * inv + skv.x;
    o.y = ny * inv + skv.y;
    o.z = nz * inv + skv.z;
    o.w = nw * inv + skv.w;
    if (do_relu) {
        o.x = fmaxf(o.x, 0.f); o.y = fmaxf(o.y, 0.f);
        o.z = fmaxf(o.z, 0.f); o.w = fmaxf(o.w, 0.f);
    }
    if (lane < 16) *(float4*)&io[(size_t)node * DCH + gl * 4] = o;
}

// ---------------- launch ----------------

extern "C" void kernel_launch(void* const* d_in, const int* in_sizes, int n_in,
                              void* d_out, int out_size, void* d_ws, size_t ws_size,
                              hipStream_t stream) {
    const float* x   = (const float*)d_in[0];
    const int*   ei  = (const int*)d_in[1];      // int32 per harness contract
    const float* Wq1 = (const float*)d_in[2];  const float* bq1 = (const float*)d_in[3];
    const float* Wk1 = (const float*)d_in[4];  const float* bk1 = (const float*)d_in[5];
    const float* Wv1 = (const float*)d_in[6];  const float* bv1 = (const float*)d_in[7];
    const float* Ws1 = (const float*)d_in[8];  const float* bs1 = (const float*)d_in[9];
    const float* Wq2 = (const float*)d_in[10]; const float* bq2 = (const float*)d_in[11];
    const float* Wk2 = (const float*)d_in[12]; const float* bk2 = (const float*)d_in[13];
    const float* Wv2 = (const float*)d_in[14]; const float* bv2 = (const float*)d_in[15];
    const float* Ws2 = (const float*)d_in[16]; const float* bs2 = (const float*)d_in[17];
    int N = in_sizes[0] / DCH;
    int E = in_sizes[1] / 2;

    char* p = (char*)d_ws;
    auto alloc = [&](size_t bytes) -> void* {
        void* r = (void*)p; p += (bytes + 255) & ~(size_t)255; return r;
    };
    float* q    = (float*)alloc((size_t)N * DCH * 4);
    float* kbuf = (float*)alloc((size_t)N * DCH * 4);
    float* vbuf = (float*)alloc((size_t)N * DCH * 4);
    float* h    = (float*)alloc((size_t)N * DCH * 4);
    int* cnt  = (int*)alloc((size_t)N * 4);
    int* fill = (int*)alloc((size_t)N * 4);
    int* offs = (int*)alloc((size_t)(N + 1) * 4);
    int* part = (int*)alloc(1024 * 4);
    int* ssrc = (int*)alloc((size_t)E * 4);
    float* outp = (float*)d_out;

    int nb = (N + 1023) / 1024;

    // CSR by dst (rebuilt every call; ws is re-poisoned before each launch)
    hipLaunchKernelGGL(zero_kernel, dim3((N + 255) / 256), dim3(256), 0, stream, cnt, N);
    hipLaunchKernelGGL(zero_kernel, dim3((N + 255) / 256), dim3(256), 0, stream, fill, N);
    hipLaunchKernelGGL(hist_kernel, dim3(1024), dim3(256), 0, stream, ei, cnt, E);
    hipLaunchKernelGGL(scan1_kernel, dim3(nb), dim3(1024), 0, stream, cnt, offs, part, N);
    hipLaunchKernelGGL(scan2_kernel, dim3(1), dim3(1024), 0, stream, part, offs + N, nb);
    hipLaunchKernelGGL(scan3_kernel, dim3(nb), dim3(1024), 0, stream, offs, part, N);
    hipLaunchKernelGGL(scatter_kernel, dim3(1024), dim3(256), 0, stream, ei, offs, fill, ssrc, E);

    // layer 1 (skip -> h, attn updates h in place, ReLU)
    hipLaunchKernelGGL(linear4_kernel, dim3((N + 63) / 64), dim3(64), 0, stream,
                       x, Wq1, bq1, Wk1, bk1, Wv1, bv1, Ws1, bs1,
                       q, kbuf, vbuf, h, N);
    hipLaunchKernelGGL(attn_kernel, dim3((N + 3) / 4), dim3(256), 0, stream,
                       q, kbuf, vbuf, offs, ssrc, h, N, 1);

    // layer 2 (skip -> d_out, attn updates d_out in place)
    hipLaunchKernelGGL(linear4_kernel, dim3((N + 63) / 64), dim3(64), 0, stream,
                       h, Wq2, bq2, Wk2, bk2, Wv2, bv2, Ws2, bs2,
                       q, kbuf, vbuf, outp, N);
    hipLaunchKernelGGL(attn_kernel, dim3((N + 3) / 4), dim3(256), 0, stream,
                       q, kbuf, vbuf, offs, ssrc, outp, N, 0);
}